// Round 2
// baseline (204.129 us; speedup 1.0000x reference)
//
#include <hip/hip_runtime.h>

// MeshTokenizer: B=64, NV=8192, NF=16384.
// Outputs concatenated flat as float32:
//   [0] input_ids        64 x 163841   @ 0
//   [1] attention_mask   64 x 163841   @ 10485824   (all ones == full region)
//   [2] codes            64x16384x3x3  @ 20971648
//   [3] discrete_face_coords (==codes) @ 30408832
//   [4] recon_faces      64x1x3x3      @ 39846016
// 159.4 MB writes + ~19 MB reads -> ~28 us roofline @6.3 TB/s.
//
// R8: SINGLE fused kernel. R7's null result (barrier removal + mask move +
// cvt = +-0) falsified the vmcnt-drain and BW-redistribution theories. The
// surviving suspects are (B) L1-thrashed random gathers on the packed table
// (32 KB table == L1 size, evicted by faces streaming; 16 different batch
// tables cycle through each CU's L1) and (C) per-dispatch fixed cost +
// device-wide drain between pack and mesh_tok.
// Fix for both: ONE kernel. Each block rebuilds its batch's packed table in
// LDS (vf4 vert loads, 4 verts/group, ds_write_b128), so gathers are LDS
// reads; pack kernel, its launch, the inter-kernel drain, and the 4 MB
// workspace round-trip are gone. LDS 51 KB -> 3 blocks/CU (fill kernel
// sustains 6.7 TB/s at ~3 waves/CU, so occupancy suffices for streaming).
// Per-wave LDS slices for ids/codes staging kept from R7 (no second barrier).

#define B_      64
#define NV_     8192
#define NF_     16384
#define ROW_    (NF_ * 10 + 1)   // 163841 (odd stride -> per-batch dword phase b&3)
#define OFF_IDS   ((size_t)0)
#define OFF_MASK  ((size_t)10485824)
#define OFF_C1    ((size_t)20971648)
#define OFF_C2    ((size_t)30408832)
#define OFF_REC   ((size_t)39846016)
#define MASK_VF4  2621456u        // 10,485,824 floats / 4

typedef float        vf4 __attribute__((ext_vector_type(4)));
typedef unsigned int vu4 __attribute__((ext_vector_type(4)));

__device__ __forceinline__ float disc1(float x) {
    // (x-LO)/(HI-LO)*128 - 0.5 == (x+1)*64 - 0.5 bit-exactly; round-half-even
    float r = rintf((x + 1.0f) * 64.0f - 0.5f);
    return fminf(fmaxf(r, 0.0f), 127.0f);
}

// One block = 256 consecutive faces of one batch (4096 blocks total).
// Phase 0: mask grid-stride stores (input-independent, issued first).
// Phase 1: build batch's packed-code table in LDS (8192 verts, 32 KB).
// Phase 2 (post-barrier): gather from LDS, stage ids/codes per-wave, stream.
__global__ __launch_bounds__(256) void mesh_tok_fused(
        const float* __restrict__ verts,
        const int*   __restrict__ faces,
        float*       __restrict__ out) {
    const int t   = threadIdx.x;
    const int w   = t >> 6;              // wave 0..3
    const int l   = t & 63;              // lane
    const int blk = blockIdx.x;
    const int b   = blk >> 6;            // batch
    const int j0  = (blk & 63) << 8;     // first face of this block
    const int j   = j0 + (w << 6) + l;   // face this thread owns

    __shared__ __align__(16) unsigned int s_tab[NV_];   // 32 KB packed codes
    __shared__ __align__(16) float s_ids[4][644];       // 2576 B/wave slice
    __shared__ __align__(16) float s_codes[4][576];     // 2304 B/wave slice

    // ---- mask: pure memset(1.0f) of the whole region, issued first so the
    // stores flow while the table is being built ----
    {
        const vf4 ones = {1.0f, 1.0f, 1.0f, 1.0f};
        vf4* m4 = (vf4*)(out + OFF_MASK);
        const unsigned int g = (unsigned int)blk * 256u + (unsigned int)t;
        for (unsigned int f4 = g; f4 < MASK_VF4; f4 += 1048576u) m4[f4] = ones;
    }

    // ---- faces indices: issue early, consumed after the barrier ----
    const int* fp = faces + ((size_t)b * NF_ + j) * 3;
    const int i0 = fp[0], i1 = fp[1], i2 = fp[2];

    // ---- table build: thread handles 8 groups of 4 verts (12 floats = 3 vf4
    // per group), packs 4 codes, one ds_write_b128 per group ----
    {
        const vf4* v4 = (const vf4*)(verts + (size_t)b * NV_ * 3);
        #pragma unroll
        for (int g = 0; g < 8; ++g) {
            const int grp = t + (g << 8);            // vert group: 4grp..4grp+3
            const vf4 va = v4[3 * grp + 0];
            const vf4 vb = v4[3 * grp + 1];
            const vf4 vc = v4[3 * grp + 2];
            const float f[12] = {va.x, va.y, va.z, va.w,
                                 vb.x, vb.y, vb.z, vb.w,
                                 vc.x, vc.y, vc.z, vc.w};
            vu4 pk4;
            #pragma unroll
            for (int k = 0; k < 4; ++k) {
                const unsigned int c0 = (unsigned int)disc1(f[3 * k + 0]);
                const unsigned int c1 = (unsigned int)disc1(f[3 * k + 1]);
                const unsigned int c2 = (unsigned int)disc1(f[3 * k + 2]);
                pk4[k] = c0 | (c1 << 8) | (c2 << 16);
            }
            *((vu4*)&s_tab[grp << 2]) = pk4;
        }
    }
    __syncthreads();

    // ---- gather from LDS table ----
    const unsigned int pk[3] = {s_tab[i0], s_tab[i1], s_tab[i2]};

    // ---- unpack: byte fields (<128) -> v_cvt_f32_ubyte{0,1,2} ----
    float code_f[9];
    #pragma unroll
    for (int vi = 0; vi < 3; ++vi) {
        code_f[vi * 3 + 0] = (float)(pk[vi] & 0xffu);
        code_f[vi * 3 + 1] = (float)((pk[vi] >> 8) & 0xffu);
        code_f[vi * 3 + 2] = (float)((pk[vi] >> 16) & 0xffu);
    }

    const size_t S   = (size_t)b * ROW_ + (size_t)j0 * 10;
    const int    p   = (int)(S & 3);                 // == b & 3
    const int    pp  = (4 - p) & 3;
    const size_t Sw  = S + (size_t)(w * 640);        // this wave's span start
    const size_t Aw  = Sw + (size_t)pp;              // 16B-aligned start
    const int    nf4 = (p == 0) ? 160 : 159;
    const int    lb  = (p == 0) ? 0 : 1;             // (p+pp)/4

    // ---- wave-local staging (phase-shifted); slice words p .. p+639 ----
    s_ids[w][p + l * 10] = (j == 0) ? -1.0f : 128.0f;   // sep of j-1 / lead pad
    #pragma unroll
    for (int k = 0; k < 9; ++k) {
        s_ids[w][p + l * 10 + 1 + k] = code_f[k];
        s_codes[w][l * 9 + k]        = code_f[k];
    }
    // no second barrier: each wave reads only its own slice (lgkmcnt ordering)

    float* out_ids = out + OFF_IDS;

    // ---- ids: head scalars + aligned vf4 body + tail scalars, per-wave ----
    {
        const vf4* s4   = (const vf4*)&s_ids[w][0];
        vf4*       ids4 = (vf4*)(out_ids + Aw);
        for (int f4 = l; f4 < nf4; f4 += 64) ids4[f4] = s4[lb + f4];
        if (l < pp)              out_ids[Sw + l] = s_ids[w][p + l];
        if (l >= 4 && l < 4 + p) out_ids[Sw + 640 - p + (l - 4)] = s_ids[w][640 + (l - 4)];
    }

    // ---- codes x2: naturally 16B-aligned, per-wave 144 vf4 ----
    {
        const size_t baseC = ((size_t)b * NF_ + (size_t)(j0 + (w << 6))) * 9;
        const vf4* sc4 = (const vf4*)&s_codes[w][0];
        vf4* c1p = (vf4*)(out + OFF_C1 + baseC);
        vf4* c2p = (vf4*)(out + OFF_C2 + baseC);
        for (int f4 = l; f4 < 144; f4 += 64) {
            vf4 v = sc4[f4];
            c1p[f4] = v;
            c2p[f4] = v;
        }
    }

    // ---- final ids pad + recon_faces (thread 0 of block holds face j0) ----
    if (t == 0) {
        if (j0 == NF_ - 256)
            out_ids[(size_t)b * ROW_ + (ROW_ - 1)] = -1.0f;
        if (j0 == 0) {  // face 0 of batch b
            float* out_rec = out + OFF_REC;
            #pragma unroll
            for (int k = 0; k < 9; ++k)
                out_rec[b * 9 + k] = (code_f[k] + 0.5f) * 0.015625f - 1.0f;
        }
    }
}

extern "C" void kernel_launch(void* const* d_in, const int* in_sizes, int n_in,
                              void* d_out, int out_size, void* d_ws, size_t ws_size,
                              hipStream_t stream) {
    const float* verts = (const float*)d_in[0];
    const int*   faces = (const int*)d_in[1];
    float*       out   = (float*)d_out;

    mesh_tok_fused<<<dim3(B_ * (NF_ / 256)), dim3(256), 0, stream>>>(verts, faces, out);
}